// Round 1
// baseline (674.515 us; speedup 1.0000x reference)
//
#include <hip/hip_runtime.h>
#include <cstdint>
#include <cmath>

typedef unsigned short ushort_t;
typedef __bf16 bf16x8 __attribute__((ext_vector_type(8)));
typedef float f32x4 __attribute__((ext_vector_type(4)));
typedef ushort_t us4 __attribute__((ext_vector_type(4)));
typedef ushort_t us8 __attribute__((ext_vector_type(8)));

#define MFMA16(a, b, c) __builtin_amdgcn_mfma_f32_16x16x32_bf16(a, b, c, 0, 0, 0)

__device__ __forceinline__ ushort_t f2bf(float f) {
    uint32_t u = __float_as_uint(f);
    u = u + 0x7fffu + ((u >> 16) & 1u);   // RNE
    return (ushort_t)(u >> 16);
}

__device__ __forceinline__ void glds16(const ushort_t* g, ushort_t* s) {
    __builtin_amdgcn_global_load_lds(
        (const __attribute__((address_space(1))) void*)(g),
        (__attribute__((address_space(3))) void*)(s), 16, 0, 0);
}

// ---------------- cast f32 -> bf16, vectorized x4 ----------------
__global__ void cast_f32_bf16_k(const float* __restrict__ in, ushort_t* __restrict__ out, int n4) {
    int i = blockIdx.x * 256 + threadIdx.x;
    if (i >= n4) return;
    float4 v = ((const float4*)in)[i];
    us4 o;
    o.x = f2bf(v.x); o.y = f2bf(v.y); o.z = f2bf(v.z); o.w = f2bf(v.w);
    ((us4*)out)[i] = o;
}

// ---------------- T5 bucket LUT: delta = j - i in [-2047, 2047] ----------------
__global__ void make_lut_k(unsigned char* __restrict__ lut) {
    int idx = blockIdx.x * 256 + threadIdx.x;
    if (idx >= 4095) return;
    int rel = idx - 2047;
    int b = (rel > 0) ? 16 : 0;
    int rp = (rel < 0) ? -rel : rel;
    int add;
    if (rp < 8) {
        add = rp;
    } else {
        // match np: correctly-rounded f32 log, then f64 divide, trunc toward zero
        float lg = (float)::log((double)rp * 0.125);
        double t = ((double)lg) / 2.772588722239781 * 8.0;
        int large = 8 + (int)t;
        add = (large < 15) ? large : 15;
    }
    lut[idx] = (unsigned char)(b + add);
}

// ---------------- position_bias writer: out2[h][i][j], float4/thread ----------------
__global__ void write_bias_k(const unsigned char* __restrict__ lut, const float* __restrict__ table,
                             float* __restrict__ out2) {
    int t = blockIdx.x * 256 + threadIdx.x;   // 16 * 2048 * 512 total
    int j4 = t & 511;
    int i = (t >> 9) & 2047;
    int h = t >> 20;
    int base = j4 * 4 - i + 2047;
    float4 v;
    v.x = table[lut[base + 0] * 16 + h];
    v.y = table[lut[base + 1] * 16 + h];
    v.z = table[lut[base + 2] * 16 + h];
    v.w = table[lut[base + 3] * 16 + h];
    ((float4*)out2)[t] = v;
}

// ---------------- GEMM: C[M,N] = A[M,K] * B[N,K]^T, bf16 in, f32 acc ----------------
// 128x128 tile, BK=64, 256 thr = 4 waves in 2x2, each wave 4x4 of 16x16x32 MFMA
template <bool F32OUT>
__global__ __launch_bounds__(256) void gemm_bt_k(const ushort_t* __restrict__ A,
                                                 const ushort_t* __restrict__ B0,
                                                 void* __restrict__ C0,
                                                 int M, int N, int K, long sB, long sC) {
    __shared__ ushort_t As[128 * 64];
    __shared__ ushort_t Bs[128 * 64];
    const int tid = threadIdx.x;
    const int l = tid & 63, w = tid >> 6;
    const int quad = l >> 4, lc = l & 15;
    const int wm = w >> 1, wn = w & 1;
    const int m0 = blockIdx.y * 128, n0 = blockIdx.x * 128;
    const ushort_t* B = B0 + (long)blockIdx.z * sB;

    f32x4 acc[4][4] = {};
    const int rA = l >> 3;
    const int cA = (l & 7) * 8;

    for (int k0 = 0; k0 < K; k0 += 64) {
#pragma unroll
        for (int t = 0; t < 4; ++t) {
            int row = w * 32 + t * 8;
            glds16(A + (size_t)(m0 + row + rA) * K + k0 + cA, &As[row * 64]);
            glds16(B + (size_t)(n0 + row + rA) * K + k0 + cA, &Bs[row * 64]);
        }
        __syncthreads();
#pragma unroll
        for (int ko = 0; ko < 2; ++ko) {
            bf16x8 af[4], bfr[4];
#pragma unroll
            for (int mt = 0; mt < 4; ++mt)
                af[mt] = *(const bf16x8*)&As[(wm * 64 + mt * 16 + lc) * 64 + ko * 32 + quad * 8];
#pragma unroll
            for (int nt = 0; nt < 4; ++nt)
                bfr[nt] = *(const bf16x8*)&Bs[(wn * 64 + nt * 16 + lc) * 64 + ko * 32 + quad * 8];
#pragma unroll
            for (int mt = 0; mt < 4; ++mt)
#pragma unroll
                for (int nt = 0; nt < 4; ++nt)
                    acc[mt][nt] = MFMA16(af[mt], bfr[nt], acc[mt][nt]);
        }
        __syncthreads();
    }
#pragma unroll
    for (int mt = 0; mt < 4; ++mt) {
#pragma unroll
        for (int nt = 0; nt < 4; ++nt) {
            int col = n0 + wn * 64 + nt * 16 + lc;
#pragma unroll
            for (int r = 0; r < 4; ++r) {
                int row = m0 + wm * 64 + mt * 16 + quad * 4 + r;
                if constexpr (F32OUT) {
                    ((float*)C0)[(size_t)row * N + col] = acc[mt][nt][r];
                } else {
                    (((ushort_t*)C0) + (long)blockIdx.z * sC)[(size_t)row * N + col] = f2bf(acc[mt][nt][r]);
                }
            }
        }
    }
}

// ---------------- flash attention with T5 bias, bf16 MFMA ----------------
// grid (16 q-tiles, 32 b*h); 256 thr = 4 waves, wave w owns q-rows [w*32, w*32+32)
__global__ __launch_bounds__(256) void attn_k(const ushort_t* __restrict__ Q,
                                              const ushort_t* __restrict__ Kg,
                                              const ushort_t* __restrict__ Vg,
                                              ushort_t* __restrict__ Ctx,
                                              const unsigned char* __restrict__ lut,
                                              const float* __restrict__ table) {
    __shared__ ushort_t Ks[128 * 64];        // K tile [j][d]
    __shared__ ushort_t Vt[64 * 144];        // V^T tile [d][j], padded stride
    __shared__ ushort_t QPs[4 * 32 * 132];   // Q tile first, then per-wave P [32][132]
    __shared__ float tabH[32];

    const int tid = threadIdx.x, l = tid & 63, w = tid >> 6;
    const int quad = l >> 4, lc = l & 15;
    const int bh = blockIdx.y, b = bh >> 4, h = bh & 15;
    const int q0 = blockIdx.x * 128;
    const size_t base_bh = (size_t)b * 2048 * 1024 + (size_t)h * 64;

    if (tid < 32) tabH[tid] = table[tid * 16 + h];

    const int rA = l >> 3, cA = (l & 7) * 8;
    // stage Q tile into QPs[0..8192)
#pragma unroll
    for (int t = 0; t < 4; ++t) {
        int row = w * 32 + t * 8;
        glds16(Q + base_bh + (size_t)(q0 + row + rA) * 1024 + cA, &QPs[row * 64]);
    }
    __syncthreads();
    bf16x8 qf[2][2];
#pragma unroll
    for (int mt = 0; mt < 2; ++mt)
#pragma unroll
        for (int ko = 0; ko < 2; ++ko)
            qf[mt][ko] = *(const bf16x8*)&QPs[(w * 32 + mt * 16 + lc) * 64 + ko * 32 + quad * 8];
    __syncthreads();   // everyone read Q before QPs is reused as Ps

    float mstate[2][4], lstate[2][4];
    f32x4 acco[2][4] = {};
#pragma unroll
    for (int mt = 0; mt < 2; ++mt)
#pragma unroll
        for (int r = 0; r < 4; ++r) { mstate[mt][r] = -1e30f; lstate[mt][r] = 0.f; }

    ushort_t* Ps = &QPs[w * 32 * 132];

    for (int kt = 0; kt < 16; ++kt) {
        const int j0 = kt * 128;
#pragma unroll
        for (int t = 0; t < 4; ++t) {
            int row = w * 32 + t * 8;
            glds16(Kg + base_bh + (size_t)(j0 + row + rA) * 1024 + cA, &Ks[row * 64]);
        }
        // V transpose-stage via registers
#pragma unroll
        for (int cc = 0; cc < 4; ++cc) {
            int c = cc * 256 + tid;
            int vj = c >> 3, d0 = (c & 7) * 8;
            us8 v = *(const us8*)(Vg + base_bh + (size_t)(j0 + vj) * 1024 + d0);
#pragma unroll
            for (int e = 0; e < 8; ++e) Vt[(d0 + e) * 144 + vj] = v[e];
        }
        __syncthreads();

        // S = Q K^T
        f32x4 accs[2][8] = {};
#pragma unroll
        for (int ko = 0; ko < 2; ++ko) {
            bf16x8 kf[8];
#pragma unroll
            for (int nt = 0; nt < 8; ++nt)
                kf[nt] = *(const bf16x8*)&Ks[(nt * 16 + lc) * 64 + ko * 32 + quad * 8];
#pragma unroll
            for (int mt = 0; mt < 2; ++mt)
#pragma unroll
                for (int nt = 0; nt < 8; ++nt)
                    accs[mt][nt] = MFMA16(qf[mt][ko], kf[nt], accs[mt][nt]);
        }
        // + bias
#pragma unroll
        for (int mt = 0; mt < 2; ++mt) {
#pragma unroll
            for (int nt = 0; nt < 8; ++nt) {
                int jg = j0 + nt * 16 + lc;
#pragma unroll
                for (int r = 0; r < 4; ++r) {
                    int ig = q0 + w * 32 + mt * 16 + quad * 4 + r;
                    accs[mt][nt][r] += tabH[lut[jg - ig + 2047]];
                }
            }
        }
        // online softmax (row = quad*4+r within tile; 16 col-lanes share a row)
#pragma unroll
        for (int mt = 0; mt < 2; ++mt) {
#pragma unroll
            for (int r = 0; r < 4; ++r) {
                float v = accs[mt][0][r];
#pragma unroll
                for (int nt = 1; nt < 8; ++nt) v = fmaxf(v, accs[mt][nt][r]);
#pragma unroll
                for (int off = 1; off < 16; off <<= 1) v = fmaxf(v, __shfl_xor(v, off, 64));
                float mo = mstate[mt][r];
                float mn = fmaxf(mo, v);
                float alpha = __expf(mo - mn);
                mstate[mt][r] = mn;
                float rs = 0.f;
#pragma unroll
                for (int nt = 0; nt < 8; ++nt) {
                    float p = __expf(accs[mt][nt][r] - mn);
                    accs[mt][nt][r] = p;
                    rs += p;
                }
#pragma unroll
                for (int off = 1; off < 16; off <<= 1) rs += __shfl_xor(rs, off, 64);
                lstate[mt][r] = lstate[mt][r] * alpha + rs;
#pragma unroll
                for (int dt = 0; dt < 4; ++dt) acco[mt][dt][r] *= alpha;
            }
        }
        // P: C-layout -> LDS (wave-private slice, stride 132 to dodge bank conflicts)
#pragma unroll
        for (int mt = 0; mt < 2; ++mt)
#pragma unroll
            for (int nt = 0; nt < 8; ++nt)
#pragma unroll
                for (int r = 0; r < 4; ++r)
                    Ps[(mt * 16 + quad * 4 + r) * 132 + nt * 16 + lc] = f2bf(accs[mt][nt][r]);
        // O += P V   (A = P rows m, B = Vt rows d)
#pragma unroll
        for (int kk = 0; kk < 4; ++kk) {
            bf16x8 af[2];
#pragma unroll
            for (int mt = 0; mt < 2; ++mt) {
                const ushort_t* p = &Ps[(mt * 16 + lc) * 132 + kk * 32 + quad * 8];
                union { bf16x8 v; us4 hh[2]; } u;
                u.hh[0] = *(const us4*)p;
                u.hh[1] = *(const us4*)(p + 4);
                af[mt] = u.v;
            }
            bf16x8 vf[4];
#pragma unroll
            for (int dt = 0; dt < 4; ++dt)
                vf[dt] = *(const bf16x8*)&Vt[(dt * 16 + lc) * 144 + kk * 32 + quad * 8];
#pragma unroll
            for (int mt = 0; mt < 2; ++mt)
#pragma unroll
                for (int dt = 0; dt < 4; ++dt)
                    acco[mt][dt] = MFMA16(af[mt], vf[dt], acco[mt][dt]);
        }
        __syncthreads();
    }
    // epilogue: divide by l, store bf16 ctx [b*2048+row][h*64+d]
#pragma unroll
    for (int mt = 0; mt < 2; ++mt) {
#pragma unroll
        for (int r = 0; r < 4; ++r) {
            float inv = 1.0f / lstate[mt][r];
            int row = q0 + w * 32 + mt * 16 + quad * 4 + r;
#pragma unroll
            for (int dt = 0; dt < 4; ++dt)
                Ctx[(size_t)(b * 2048 + row) * 1024 + h * 64 + dt * 16 + lc] =
                    f2bf(acco[mt][dt][r] * inv);
        }
    }
}

extern "C" void kernel_launch(void* const* d_in, const int* in_sizes, int n_in,
                              void* d_out, int out_size, void* d_ws, size_t ws_size,
                              hipStream_t stream) {
    const float* hidden = (const float*)d_in[0];
    const float* Wq = (const float*)d_in[1];
    const float* Wk = (const float*)d_in[2];
    const float* Wv = (const float*)d_in[3];
    const float* Wo = (const float*)d_in[4];
    const float* table = (const float*)d_in[5];

    char* ws = (char*)d_ws;
    ushort_t* Xb = (ushort_t*)(ws);                          // 4,194,304 bf16
    ushort_t* Wb = (ushort_t*)(ws + 8388608);                // 4 x 1,048,576 bf16 (q,k,v,o)
    ushort_t* QKV = (ushort_t*)(ws + 16777216);              // 3 x 4,194,304 bf16
    ushort_t* Ctx = (ushort_t*)(ws + 41943040);              // 4,194,304 bf16
    unsigned char* lut = (unsigned char*)(ws + 50331648);    // 4095 bytes

    float* out0 = (float*)d_out;
    float* out1 = out0 + 4194304;

    cast_f32_bf16_k<<<4096, 256, 0, stream>>>(hidden, Xb, 1048576);
    cast_f32_bf16_k<<<1024, 256, 0, stream>>>(Wq, Wb + 0, 262144);
    cast_f32_bf16_k<<<1024, 256, 0, stream>>>(Wk, Wb + 1048576, 262144);
    cast_f32_bf16_k<<<1024, 256, 0, stream>>>(Wv, Wb + 2097152, 262144);
    cast_f32_bf16_k<<<1024, 256, 0, stream>>>(Wo, Wb + 3145728, 262144);
    make_lut_k<<<16, 256, 0, stream>>>(lut);
    write_bias_k<<<65536, 256, 0, stream>>>(lut, table, out1);

    gemm_bt_k<false><<<dim3(8, 32, 3), 256, 0, stream>>>(Xb, Wb, (void*)QKV,
                                                         4096, 1024, 1024, 1048576, 4194304);
    attn_k<<<dim3(16, 32), 256, 0, stream>>>(QKV, QKV + 4194304, QKV + 8388608, Ctx, lut, table);
    gemm_bt_k<true><<<dim3(8, 32, 1), 256, 0, stream>>>(Ctx, Wb + 3145728, (void*)out0,
                                                        4096, 1024, 1024, 0, 0);
}

// Round 2
// 494.780 us; speedup vs baseline: 1.3633x; 1.3633x over previous
//
#include <hip/hip_runtime.h>
#include <cstdint>
#include <cmath>

typedef unsigned short ushort_t;
typedef __bf16 bf16x8 __attribute__((ext_vector_type(8)));
typedef float f32x4 __attribute__((ext_vector_type(4)));
typedef ushort_t us4 __attribute__((ext_vector_type(4)));
typedef ushort_t us8 __attribute__((ext_vector_type(8)));

#define MFMA16(a, b, c) __builtin_amdgcn_mfma_f32_16x16x32_bf16(a, b, c, 0, 0, 0)

__device__ __forceinline__ ushort_t f2bf(float f) {
    uint32_t u = __float_as_uint(f);
    u = u + 0x7fffu + ((u >> 16) & 1u);   // RNE
    return (ushort_t)(u >> 16);
}

__device__ __forceinline__ void glds16(const ushort_t* g, ushort_t* s) {
    __builtin_amdgcn_global_load_lds(
        (const __attribute__((address_space(1))) void*)(g),
        (__attribute__((address_space(3))) void*)(s), 16, 0, 0);
}

// ---------------- cast f32 -> bf16, vectorized x4 ----------------
__global__ void cast_f32_bf16_k(const float* __restrict__ in, ushort_t* __restrict__ out, int n4) {
    int i = blockIdx.x * 256 + threadIdx.x;
    if (i >= n4) return;
    float4 v = ((const float4*)in)[i];
    us4 o;
    o.x = f2bf(v.x); o.y = f2bf(v.y); o.z = f2bf(v.z); o.w = f2bf(v.w);
    ((us4*)out)[i] = o;
}

// ---------------- T5 bucket LUT: delta = j - i in [-2047, 2047] ----------------
__global__ void make_lut_k(unsigned char* __restrict__ lut) {
    int idx = blockIdx.x * 256 + threadIdx.x;
    if (idx >= 4095) return;
    int rel = idx - 2047;
    int b = (rel > 0) ? 16 : 0;
    int rp = (rel < 0) ? -rel : rel;
    int add;
    if (rp < 8) {
        add = rp;
    } else {
        // match np: correctly-rounded f32 log, then f64 divide, trunc toward zero
        float lg = (float)::log((double)rp * 0.125);
        double t = ((double)lg) / 2.772588722239781 * 8.0;
        int large = 8 + (int)t;
        add = (large < 15) ? large : 15;
    }
    lut[idx] = (unsigned char)(b + add);
}

// ---------------- position_bias writer: out2[h][i][j], float4/thread ----------------
__global__ void write_bias_k(const unsigned char* __restrict__ lut, const float* __restrict__ table,
                             float* __restrict__ out2) {
    int t = blockIdx.x * 256 + threadIdx.x;   // 16 * 2048 * 512 total
    int j4 = t & 511;
    int i = (t >> 9) & 2047;
    int h = t >> 20;
    int base = j4 * 4 - i + 2047;
    float4 v;
    v.x = table[lut[base + 0] * 16 + h];
    v.y = table[lut[base + 1] * 16 + h];
    v.z = table[lut[base + 2] * 16 + h];
    v.w = table[lut[base + 3] * 16 + h];
    ((float4*)out2)[t] = v;
}

// ---------------- GEMM: C[M,N] = A[M,K] * B[N,K]^T, bf16 in, f32 acc ----------------
// 128x128 tile, BK=64, XOR-swizzled LDS (conflict-free b128 frag reads).
// MODE 0: bf16 out row-major (+z batch); MODE 1: f32 out; MODE 2: bf16 out, V^T split addressing
template <int MODE>
__global__ __launch_bounds__(256) void gemm_bt_k(const ushort_t* __restrict__ A,
                                                 const ushort_t* __restrict__ B0,
                                                 void* __restrict__ C0,
                                                 int M, int N, int K, long sB, long sC) {
    __shared__ ushort_t As[128 * 64];
    __shared__ ushort_t Bs[128 * 64];
    const int tid = threadIdx.x;
    const int l = tid & 63, w = tid >> 6;
    const int quad = l >> 4, lc = l & 15;
    const int wm = w >> 1, wn = w & 1;
    const int m0 = blockIdx.y * 128, n0 = blockIdx.x * 128;
    const ushort_t* B = B0 + (long)blockIdx.z * sB;

    f32x4 acc[4][4] = {};
    const int rA = l >> 3;
    const int cA = ((l & 7) ^ rA) * 8;   // swizzled global chunk

    for (int k0 = 0; k0 < K; k0 += 64) {
#pragma unroll
        for (int t = 0; t < 4; ++t) {
            int row = w * 32 + t * 8;
            glds16(A + (size_t)(m0 + row + rA) * K + k0 + cA, &As[row * 64]);
            glds16(B + (size_t)(n0 + row + rA) * K + k0 + cA, &Bs[row * 64]);
        }
        __syncthreads();
#pragma unroll
        for (int ko = 0; ko < 2; ++ko) {
            const int ch = (((ko * 4 + quad) ^ (lc & 7))) * 8;
            bf16x8 af[4], bfr[4];
#pragma unroll
            for (int mt = 0; mt < 4; ++mt)
                af[mt] = *(const bf16x8*)&As[(wm * 64 + mt * 16 + lc) * 64 + ch];
#pragma unroll
            for (int nt = 0; nt < 4; ++nt)
                bfr[nt] = *(const bf16x8*)&Bs[(wn * 64 + nt * 16 + lc) * 64 + ch];
#pragma unroll
            for (int mt = 0; mt < 4; ++mt)
#pragma unroll
                for (int nt = 0; nt < 4; ++nt)
                    acc[mt][nt] = MFMA16(af[mt], bfr[nt], acc[mt][nt]);
        }
        __syncthreads();
    }
#pragma unroll
    for (int mt = 0; mt < 4; ++mt) {
#pragma unroll
        for (int nt = 0; nt < 4; ++nt) {
            int col = n0 + wn * 64 + nt * 16 + lc;
#pragma unroll
            for (int r = 0; r < 4; ++r) {
                int row = m0 + wm * 64 + mt * 16 + quad * 4 + r;
                if constexpr (MODE == 1) {
                    ((float*)C0)[(size_t)row * N + col] = acc[mt][nt][r];
                } else if constexpr (MODE == 0) {
                    (((ushort_t*)C0) + (long)blockIdx.z * sC)[(size_t)row * N + col] = f2bf(acc[mt][nt][r]);
                } else {
                    // row = feature f, col = token (b*2048+j): write VT[(b*1024+f)*2048 + j]
                    ((ushort_t*)C0)[(size_t)(col >> 11) * 2097152 + (size_t)row * 2048 + (col & 2047)] =
                        f2bf(acc[mt][nt][r]);
                }
            }
        }
    }
}

// ---------------- flash attention, S^T = K*Q^T orientation ----------------
// grid (16 q-tiles, 32 bh); 4 waves, wave w owns q-rows [w*32, w*32+32)
__global__ __launch_bounds__(256, 3) void attn_k(const ushort_t* __restrict__ Qg,
                                                 const ushort_t* __restrict__ Kg,
                                                 const ushort_t* __restrict__ VTg,
                                                 ushort_t* __restrict__ Ctx,
                                                 const unsigned char* __restrict__ lut,
                                                 const float* __restrict__ table) {
    __shared__ ushort_t Ks[128 * 64];    // [j][d] swizzled
    __shared__ ushort_t VTs[64 * 128];   // [d][j] swizzled
    __shared__ ushort_t QP[128 * 64];    // Q tile, then per-wave P^T chunks (32x36 u16 each)
    __shared__ float biasb[256];         // bias diagonal for current j-tile

    const int tid = threadIdx.x, l = tid & 63, w = tid >> 6;
    const int quad = l >> 4, lc = l & 15;
    const int bh = blockIdx.y, b = bh >> 4, h = bh & 15;
    const int q0 = blockIdx.x * 128;
    const size_t tokbase = (size_t)b * 2048;

    const int rK = l >> 3;                // row within 8-row glds16 group
    const int cK = ((l & 7) ^ rK) * 8;    // swizzled source chunk (u16 offset)
    const int rV = l >> 4;
    const int cVi = l & 15;

    // ---- stage Q tile + K/V tile for kt=0 + bias diagonal ----
#pragma unroll
    for (int t = 0; t < 4; ++t) {
        int row0 = w * 32 + t * 8;
        glds16(Qg + (tokbase + q0 + row0 + rK) * 1024 + h * 64 + cK, &QP[row0 * 64]);
        glds16(Kg + (tokbase + row0 + rK) * 1024 + h * 64 + cK, &Ks[row0 * 64]);
    }
#pragma unroll
    for (int t = 0; t < 4; ++t) {
        int row0 = w * 16 + t * 4;
        int rsw = ((t & 1) * 4 + rV) & 7;
        int csw = (cVi & 8) | ((cVi & 7) ^ rsw);
        glds16(VTg + (size_t)(b * 1024 + h * 64 + row0 + rV) * 2048 + csw * 8, &VTs[row0 * 128]);
    }
    if (tid < 255) biasb[tid] = table[(int)lut[0 - q0 + tid + 1920] * 16 + h];
    __syncthreads();

    // Q fragments (B-operand): lane holds Q[w*32+nt*16+lc][ko*32+quad*8+i]
    bf16x8 qf[2][2];
#pragma unroll
    for (int nt = 0; nt < 2; ++nt)
#pragma unroll
        for (int ko = 0; ko < 2; ++ko) {
            int row = w * 32 + nt * 16 + lc;
            int ch = ((ko * 4 + quad) ^ (lc & 7)) * 8;
            qf[nt][ko] = *(const bf16x8*)&QP[row * 64 + ch];
        }
    __syncthreads();   // all qf loaded before QP is reused as P^T chunks

    float mstate[2] = {-3.0e38f, -3.0e38f};
    float lstate[2] = {0.f, 0.f};
    f32x4 acco[4][2] = {};
    ushort_t* Pw = &QP[w * 1152];          // 32x36 u16, wave-private
    const int cb0 = quad * 4 - (w * 32 + lc) + 127;

    for (int kt = 0; kt < 16; ++kt) {
        const int j0 = kt * 128;
        // ---- S^T = K Q^T : D[j][q], A = K rows, B = Q rows ----
        f32x4 accs[8][2] = {};
#pragma unroll
        for (int ko = 0; ko < 2; ++ko) {
            const int ch = ((ko * 4 + quad) ^ (lc & 7)) * 8;
#pragma unroll
            for (int mt = 0; mt < 8; ++mt) {
                bf16x8 kf = *(const bf16x8*)&Ks[(mt * 16 + lc) * 64 + ch];
                accs[mt][0] = MFMA16(kf, qf[0][ko], accs[mt][0]);
                accs[mt][1] = MFMA16(kf, qf[1][ko], accs[mt][1]);
            }
        }
        // ---- + bias (from LDS diagonal; r-offsets merge into ds_read2) ----
#pragma unroll
        for (int mt = 0; mt < 8; ++mt)
#pragma unroll
            for (int nt = 0; nt < 2; ++nt)
#pragma unroll
                for (int r = 0; r < 4; ++r)
                    accs[mt][nt][r] += biasb[cb0 + (mt - nt) * 16 + r];
        // ---- online softmax: q-row = nt*16+lc, spread over 4 quad-lanes ----
#pragma unroll
        for (int nt = 0; nt < 2; ++nt) {
            float mx = accs[0][nt][0];
#pragma unroll
            for (int mt = 0; mt < 8; ++mt)
#pragma unroll
                for (int r = 0; r < 4; ++r) mx = fmaxf(mx, accs[mt][nt][r]);
            mx = fmaxf(mx, __shfl_xor(mx, 16, 64));
            mx = fmaxf(mx, __shfl_xor(mx, 32, 64));
            float mo = mstate[nt], mn = fmaxf(mo, mx);
            float alpha = __expf(mo - mn);
            mstate[nt] = mn;
            float rs = 0.f;
#pragma unroll
            for (int mt = 0; mt < 8; ++mt)
#pragma unroll
                for (int r = 0; r < 4; ++r) {
                    float p = __expf(accs[mt][nt][r] - mn);
                    accs[mt][nt][r] = p;
                    rs += p;
                }
            rs += __shfl_xor(rs, 16, 64);
            rs += __shfl_xor(rs, 32, 64);
            lstate[nt] = lstate[nt] * alpha + rs;
#pragma unroll
            for (int dt = 0; dt < 4; ++dt) acco[dt][nt] *= alpha;
        }
        // ---- O^T += V^T P^T, P^T chunked through wave-private LDS ----
#pragma unroll
        for (int kk = 0; kk < 4; ++kk) {
#pragma unroll
            for (int half = 0; half < 2; ++half) {
                int mt = kk * 2 + half;
#pragma unroll
                for (int nt = 0; nt < 2; ++nt)
#pragma unroll
                    for (int r = 0; r < 4; ++r)
                        Pw[(half * 16 + quad * 4 + r) * 36 + nt * 16 + lc] = f2bf(accs[mt][nt][r]);
            }
            bf16x8 pf[2];
#pragma unroll
            for (int nt = 0; nt < 2; ++nt) {
                union { bf16x8 v; ushort_t s[8]; } u;
#pragma unroll
                for (int i = 0; i < 8; ++i) u.s[i] = Pw[(quad * 8 + i) * 36 + nt * 16 + lc];
                pf[nt] = u.v;
            }
            bf16x8 vf[4];
#pragma unroll
            for (int dt = 0; dt < 4; ++dt) {
                int ch = kk * 4 + quad;
                int chs = ((ch & 8) | ((ch & 7) ^ (lc & 7))) * 8;
                vf[dt] = *(const bf16x8*)&VTs[(dt * 16 + lc) * 128 + chs];
            }
#pragma unroll
            for (int dt = 0; dt < 4; ++dt)
#pragma unroll
                for (int nt = 0; nt < 2; ++nt)
                    acco[dt][nt] = MFMA16(vf[dt], pf[nt], acco[dt][nt]);
        }
        __syncthreads();
        if (kt < 15) {
            const int jn = j0 + 128;
#pragma unroll
            for (int t = 0; t < 4; ++t) {
                int row0 = w * 32 + t * 8;
                glds16(Kg + (tokbase + jn + row0 + rK) * 1024 + h * 64 + cK, &Ks[row0 * 64]);
            }
#pragma unroll
            for (int t = 0; t < 4; ++t) {
                int row0 = w * 16 + t * 4;
                int rsw = ((t & 1) * 4 + rV) & 7;
                int csw = (cVi & 8) | ((cVi & 7) ^ rsw);
                glds16(VTg + (size_t)(b * 1024 + h * 64 + row0 + rV) * 2048 + jn + csw * 8,
                       &VTs[row0 * 128]);
            }
            if (tid < 255) biasb[tid] = table[(int)lut[jn - q0 + tid + 1920] * 16 + h];
            __syncthreads();
        }
    }
    // ---- epilogue: O^T lane holds (d = dt*16+quad*4+r, q = w*32+nt*16+lc) ----
#pragma unroll
    for (int nt = 0; nt < 2; ++nt) {
        float inv = 1.0f / lstate[nt];
        size_t row = tokbase + q0 + w * 32 + nt * 16 + lc;
#pragma unroll
        for (int dt = 0; dt < 4; ++dt) {
            us4 o;
#pragma unroll
            for (int r = 0; r < 4; ++r) o[r] = f2bf(acco[dt][nt][r] * inv);
            *(us4*)&Ctx[row * 1024 + h * 64 + dt * 16 + quad * 4] = o;
        }
    }
}

extern "C" void kernel_launch(void* const* d_in, const int* in_sizes, int n_in,
                              void* d_out, int out_size, void* d_ws, size_t ws_size,
                              hipStream_t stream) {
    const float* hidden = (const float*)d_in[0];
    const float* Wq = (const float*)d_in[1];
    const float* Wk = (const float*)d_in[2];
    const float* Wv = (const float*)d_in[3];
    const float* Wo = (const float*)d_in[4];
    const float* table = (const float*)d_in[5];

    char* ws = (char*)d_ws;
    ushort_t* Xb  = (ushort_t*)(ws);                    // [4096][1024] bf16
    ushort_t* Wb  = (ushort_t*)(ws + 8388608);          // Wq,Wk,Wv,Wo each [1024][1024]
    ushort_t* Qg  = (ushort_t*)(ws + 16777216);         // [4096][1024]
    ushort_t* Kgp = (ushort_t*)(ws + 25165824);         // [4096][1024]
    ushort_t* VTg = (ushort_t*)(ws + 33554432);         // [(b*1024+f)][2048]
    ushort_t* Ctx = (ushort_t*)(ws + 41943040);         // [4096][1024]
    unsigned char* lutp = (unsigned char*)(ws + 50331648);

    float* out0 = (float*)d_out;
    float* out1 = out0 + 4194304;

    cast_f32_bf16_k<<<4096, 256, 0, stream>>>(hidden, Xb, 1048576);
    cast_f32_bf16_k<<<1024, 256, 0, stream>>>(Wq, Wb + 0, 262144);
    cast_f32_bf16_k<<<1024, 256, 0, stream>>>(Wk, Wb + 1048576, 262144);
    cast_f32_bf16_k<<<1024, 256, 0, stream>>>(Wv, Wb + 2097152, 262144);
    cast_f32_bf16_k<<<1024, 256, 0, stream>>>(Wo, Wb + 3145728, 262144);
    make_lut_k<<<16, 256, 0, stream>>>(lutp);
    write_bias_k<<<65536, 256, 0, stream>>>(lutp, table, out1);

    // Q, K projections: C[token][feat] bf16
    gemm_bt_k<0><<<dim3(8, 32, 2), 256, 0, stream>>>(Xb, Wb, (void*)Qg,
                                                     4096, 1024, 1024, 1048576, 4194304);
    // V^T: C[f][token] -> VT[(b*1024+f)][j]
    gemm_bt_k<2><<<dim3(32, 8, 1), 256, 0, stream>>>(Wb + 2097152, Xb, (void*)VTg,
                                                     1024, 4096, 1024, 0, 0);
    attn_k<<<dim3(16, 32), 256, 0, stream>>>(Qg, Kgp, VTg, Ctx, lutp, table);
    gemm_bt_k<1><<<dim3(8, 32, 1), 256, 0, stream>>>(Ctx, Wb + 3145728, (void*)out0,
                                                     4096, 1024, 1024, 0, 0);
}

// Round 3
// 477.388 us; speedup vs baseline: 1.4129x; 1.0364x over previous
//
#include <hip/hip_runtime.h>
#include <cstdint>
#include <cmath>

typedef unsigned short ushort_t;
typedef __bf16 bf16x8 __attribute__((ext_vector_type(8)));
typedef float f32x4 __attribute__((ext_vector_type(4)));
typedef ushort_t us4 __attribute__((ext_vector_type(4)));
typedef ushort_t us8 __attribute__((ext_vector_type(8)));

#define MFMA16(a, b, c) __builtin_amdgcn_mfma_f32_16x16x32_bf16(a, b, c, 0, 0, 0)
#define LOG2E 1.4426950408889634f

__device__ __forceinline__ ushort_t f2bf(float f) {
    uint32_t u = __float_as_uint(f);
    u = u + 0x7fffu + ((u >> 16) & 1u);   // RNE
    return (ushort_t)(u >> 16);
}

__device__ __forceinline__ void glds16(const ushort_t* g, ushort_t* s) {
    __builtin_amdgcn_global_load_lds(
        (const __attribute__((address_space(1))) void*)(g),
        (__attribute__((address_space(3))) void*)(s), 16, 0, 0);
}

// ---------------- fused cast f32 -> bf16 (Wq pre-scaled by log2e) ----------------
__global__ void cast_all_k(const float* __restrict__ x, const float* __restrict__ wq,
                           const float* __restrict__ wk, const float* __restrict__ wv,
                           const float* __restrict__ wo, ushort_t* __restrict__ xb,
                           ushort_t* __restrict__ wb) {
    int id = blockIdx.x, t = threadIdx.x;
    const float* src;
    ushort_t* dst;
    int idx;
    float scale = 1.0f;
    if (id < 4096) {
        src = x; dst = xb; idx = id * 256 + t;
    } else {
        int r = (id - 4096) >> 10;
        idx = ((id - 4096) & 1023) * 256 + t;
        src = (r == 0) ? wq : (r == 1) ? wk : (r == 2) ? wv : wo;
        dst = wb + (size_t)r * 1048576;
        if (r == 0) scale = LOG2E;
    }
    float4 v = ((const float4*)src)[idx];
    us4 o;
    o.x = f2bf(v.x * scale); o.y = f2bf(v.y * scale);
    o.z = f2bf(v.z * scale); o.w = f2bf(v.w * scale);
    ((us4*)dst)[idx] = o;
}

// ---------------- T5 bucket LUT: delta = j - i in [-2047, 2047] ----------------
__global__ void make_lut_k(unsigned char* __restrict__ lut) {
    int idx = blockIdx.x * 256 + threadIdx.x;
    if (idx >= 4095) return;
    int rel = idx - 2047;
    int b = (rel > 0) ? 16 : 0;
    int rp = (rel < 0) ? -rel : rel;
    int add;
    if (rp < 8) {
        add = rp;
    } else {
        // match np: correctly-rounded f32 log, then f64 divide, trunc toward zero
        float lg = (float)::log((double)rp * 0.125);
        double t = ((double)lg) / 2.772588722239781 * 8.0;
        int large = 8 + (int)t;
        add = (large < 15) ? large : 15;
    }
    lut[idx] = (unsigned char)(b + add);
}

// ---------------- position_bias writer: out2[h][i][j], float4/thread ----------------
__global__ void write_bias_k(const unsigned char* __restrict__ lut, const float* __restrict__ table,
                             float* __restrict__ out2) {
    int t = blockIdx.x * 256 + threadIdx.x;   // 16 * 2048 * 512 total
    int j4 = t & 511;
    int i = (t >> 9) & 2047;
    int h = t >> 20;
    int base = j4 * 4 - i + 2047;
    float4 v;
    v.x = table[lut[base + 0] * 16 + h];
    v.y = table[lut[base + 1] * 16 + h];
    v.z = table[lut[base + 2] * 16 + h];
    v.w = table[lut[base + 3] * 16 + h];
    ((float4*)out2)[t] = v;
}

// ---------------- GEMM: C[M,N] = A[M,K] * B[N,K]^T, bf16 in, f32 acc ----------------
// 128x128 tile, BK=64, XOR-swizzled LDS (conflict-free b128 frag reads).
// MODE 0: bf16 out row-major (+z batch); MODE 1: f32 out; MODE 2: bf16 out, V^T split addressing
template <int MODE>
__global__ __launch_bounds__(256) void gemm_bt_k(const ushort_t* __restrict__ A,
                                                 const ushort_t* __restrict__ B0,
                                                 void* __restrict__ C0,
                                                 int M, int N, int K, long sB, long sC) {
    __shared__ ushort_t As[128 * 64];
    __shared__ ushort_t Bs[128 * 64];
    const int tid = threadIdx.x;
    const int l = tid & 63, w = tid >> 6;
    const int quad = l >> 4, lc = l & 15;
    const int wm = w >> 1, wn = w & 1;
    const int m0 = blockIdx.y * 128, n0 = blockIdx.x * 128;
    const ushort_t* B = B0 + (long)blockIdx.z * sB;

    f32x4 acc[4][4] = {};
    const int rA = l >> 3;
    const int cA = ((l & 7) ^ rA) * 8;   // swizzled global chunk

    for (int k0 = 0; k0 < K; k0 += 64) {
#pragma unroll
        for (int t = 0; t < 4; ++t) {
            int row = w * 32 + t * 8;
            glds16(A + (size_t)(m0 + row + rA) * K + k0 + cA, &As[row * 64]);
            glds16(B + (size_t)(n0 + row + rA) * K + k0 + cA, &Bs[row * 64]);
        }
        __syncthreads();
#pragma unroll
        for (int ko = 0; ko < 2; ++ko) {
            const int ch = (((ko * 4 + quad) ^ (lc & 7))) * 8;
            bf16x8 af[4], bfr[4];
#pragma unroll
            for (int mt = 0; mt < 4; ++mt)
                af[mt] = *(const bf16x8*)&As[(wm * 64 + mt * 16 + lc) * 64 + ch];
#pragma unroll
            for (int nt = 0; nt < 4; ++nt)
                bfr[nt] = *(const bf16x8*)&Bs[(wn * 64 + nt * 16 + lc) * 64 + ch];
#pragma unroll
            for (int mt = 0; mt < 4; ++mt)
#pragma unroll
                for (int nt = 0; nt < 4; ++nt)
                    acc[mt][nt] = MFMA16(af[mt], bfr[nt], acc[mt][nt]);
        }
        __syncthreads();
    }
#pragma unroll
    for (int mt = 0; mt < 4; ++mt) {
#pragma unroll
        for (int nt = 0; nt < 4; ++nt) {
            int col = n0 + wn * 64 + nt * 16 + lc;
#pragma unroll
            for (int r = 0; r < 4; ++r) {
                int row = m0 + wm * 64 + mt * 16 + quad * 4 + r;
                if constexpr (MODE == 1) {
                    ((float*)C0)[(size_t)row * N + col] = acc[mt][nt][r];
                } else if constexpr (MODE == 0) {
                    (((ushort_t*)C0) + (long)blockIdx.z * sC)[(size_t)row * N + col] = f2bf(acc[mt][nt][r]);
                } else {
                    // row = feature f, col = token (b*2048+j): write VT[(b*1024+f)*2048 + j]
                    ((ushort_t*)C0)[(size_t)(col >> 11) * 2097152 + (size_t)row * 2048 + (col & 2047)] =
                        f2bf(acc[mt][nt][r]);
                }
            }
        }
    }
}

// ---------------- flash attention, S^T = K*Q^T, exp2 domain, packed P ----------------
// 1-D grid 512: bh = id&31 (XCD-local K/V reuse), qt = id>>5. 4 waves, wave w owns q [w*32, w*32+32)
__global__ __launch_bounds__(256, 2) void attn_k(const ushort_t* __restrict__ Qg,
                                                 const ushort_t* __restrict__ Kg,
                                                 const ushort_t* __restrict__ VTg,
                                                 ushort_t* __restrict__ Ctx,
                                                 const unsigned char* __restrict__ lut,
                                                 const float* __restrict__ table) {
    __shared__ ushort_t Ks[128 * 64];    // [j][d] swizzled
    __shared__ ushort_t VTs[64 * 128];   // [d][j] swizzled
    __shared__ ushort_t QP[128 * 64];    // Q tile, then per-wave packed P [q][j-chunk]
    __shared__ float biasb[256];         // bias diagonal (pre-scaled by log2e)

    const int tid = threadIdx.x, l = tid & 63, w = tid >> 6;
    const int quad = l >> 4, lc = l & 15;
    const int id = blockIdx.x;
    const int bh = id & 31, b = bh >> 4, h = bh & 15;
    const int q0 = (id >> 5) * 128;
    const size_t tokbase = (size_t)b * 2048;

    const int rK = l >> 3;
    const int cK = ((l & 7) ^ rK) * 8;
    const int rV = l >> 4;
    const int cVi = l & 15;

    // ---- stage Q tile + K/V tile for kt=0 + bias diagonal ----
#pragma unroll
    for (int t = 0; t < 4; ++t) {
        int row0 = w * 32 + t * 8;
        glds16(Qg + (tokbase + q0 + row0 + rK) * 1024 + h * 64 + cK, &QP[row0 * 64]);
        glds16(Kg + (tokbase + row0 + rK) * 1024 + h * 64 + cK, &Ks[row0 * 64]);
    }
#pragma unroll
    for (int t = 0; t < 4; ++t) {
        int row0 = w * 16 + t * 4;
        int rsw = ((t & 1) * 4 + rV) & 7;
        int csw = (cVi & 8) | ((cVi & 7) ^ rsw);
        glds16(VTg + (size_t)(b * 1024 + h * 64 + row0 + rV) * 2048 + csw * 8, &VTs[row0 * 128]);
    }
    if (tid < 255) biasb[tid] = table[(int)lut[0 - q0 + tid + 1920] * 16 + h] * LOG2E;
    __syncthreads();

    // Q fragments (B-operand): lane holds Q[w*32+nt*16+lc][ko*32+quad*8+i]
    bf16x8 qf[2][2];
#pragma unroll
    for (int nt = 0; nt < 2; ++nt)
#pragma unroll
        for (int ko = 0; ko < 2; ++ko) {
            int row = w * 32 + nt * 16 + lc;
            int ch = ((ko * 4 + quad) ^ (lc & 7)) * 8;
            qf[nt][ko] = *(const bf16x8*)&QP[row * 64 + ch];
        }
    __syncthreads();   // all qf loaded before QP is reused as packed P

    float mstate[2] = {-1e30f, -1e30f};
    float lstate[2] = {0.f, 0.f};
    f32x4 acco[4][2] = {};
    ushort_t* Pw = &QP[w * 1280];          // 32 q-rows x 40 u16 (32 j + pad)
    const int cb0 = quad * 4 - (w * 32 + lc) + 127;
    const int cxor = lc & 3;               // P chunk swizzle

    for (int kt = 0; kt < 16; ++kt) {
        const int j0 = kt * 128;
        // ---- S^T = K Q^T : D[j][q], A = K rows, B = Q rows (Q pre-scaled by log2e) ----
        f32x4 accs[8][2] = {};
#pragma unroll
        for (int ko = 0; ko < 2; ++ko) {
            const int ch = ((ko * 4 + quad) ^ (lc & 7)) * 8;
#pragma unroll
            for (int mt = 0; mt < 8; ++mt) {
                bf16x8 kf = *(const bf16x8*)&Ks[(mt * 16 + lc) * 64 + ch];
                accs[mt][0] = MFMA16(kf, qf[0][ko], accs[mt][0]);
                accs[mt][1] = MFMA16(kf, qf[1][ko], accs[mt][1]);
            }
        }
        // ---- + bias: 9 distinct d = mt-nt vectors of 4 consecutive floats ----
        f32x4 bv[9];
#pragma unroll
        for (int d = 0; d < 9; ++d)
#pragma unroll
            for (int r = 0; r < 4; ++r) bv[d][r] = biasb[cb0 + (d - 1) * 16 + r];
#pragma unroll
        for (int mt = 0; mt < 8; ++mt)
#pragma unroll
            for (int nt = 0; nt < 2; ++nt)
                accs[mt][nt] += bv[mt - nt + 1];
        // ---- online softmax in exp2 domain: q-row = nt*16+lc over 4 quad-lanes ----
#pragma unroll
        for (int nt = 0; nt < 2; ++nt) {
            float mx = accs[0][nt][0];
#pragma unroll
            for (int mt = 0; mt < 8; ++mt)
#pragma unroll
                for (int r = 0; r < 4; ++r) mx = fmaxf(mx, accs[mt][nt][r]);
            mx = fmaxf(mx, __shfl_xor(mx, 16, 64));
            mx = fmaxf(mx, __shfl_xor(mx, 32, 64));
            float mo = mstate[nt], mn = fmaxf(mo, mx);
            float alpha = exp2f(mo - mn);
            mstate[nt] = mn;
            float rs = 0.f;
#pragma unroll
            for (int mt = 0; mt < 8; ++mt)
#pragma unroll
                for (int r = 0; r < 4; ++r) {
                    float p = exp2f(accs[mt][nt][r] - mn);
                    accs[mt][nt][r] = p;
                    rs += p;
                }
            rs += __shfl_xor(rs, 16, 64);
            rs += __shfl_xor(rs, 32, 64);
            lstate[nt] = lstate[nt] * alpha + rs;
#pragma unroll
            for (int dt = 0; dt < 4; ++dt) acco[dt][nt] *= alpha;
        }
        // ---- O^T += V^T P^T; P packed as [q][j-chunk] (b64 writes, b128 reads) ----
#pragma unroll
        for (int kk = 0; kk < 4; ++kk) {
#pragma unroll
            for (int half = 0; half < 2; ++half) {
                int mt = kk * 2 + half;
                int c = half * 2 + (quad >> 1);
                int coff = ((c ^ cxor) * 8 + (quad & 1) * 4);
#pragma unroll
                for (int nt = 0; nt < 2; ++nt) {
                    us4 o;
#pragma unroll
                    for (int r = 0; r < 4; ++r) o[r] = f2bf(accs[mt][nt][r]);
                    *(us4*)&Pw[(nt * 16 + lc) * 40 + coff] = o;
                }
            }
            bf16x8 pf[2];
#pragma unroll
            for (int nt = 0; nt < 2; ++nt)
                pf[nt] = *(const bf16x8*)&Pw[(nt * 16 + lc) * 40 + (quad ^ cxor) * 8];
            bf16x8 vf[4];
#pragma unroll
            for (int dt = 0; dt < 4; ++dt) {
                int ch = kk * 4 + quad;
                int chs = ((ch & 8) | ((ch & 7) ^ (lc & 7))) * 8;
                vf[dt] = *(const bf16x8*)&VTs[(dt * 16 + lc) * 128 + chs];
            }
#pragma unroll
            for (int dt = 0; dt < 4; ++dt)
#pragma unroll
                for (int nt = 0; nt < 2; ++nt)
                    acco[dt][nt] = MFMA16(vf[dt], pf[nt], acco[dt][nt]);
        }
        __syncthreads();
        if (kt < 15) {
            const int jn = j0 + 128;
#pragma unroll
            for (int t = 0; t < 4; ++t) {
                int row0 = w * 32 + t * 8;
                glds16(Kg + (tokbase + jn + row0 + rK) * 1024 + h * 64 + cK, &Ks[row0 * 64]);
            }
#pragma unroll
            for (int t = 0; t < 4; ++t) {
                int row0 = w * 16 + t * 4;
                int rsw = ((t & 1) * 4 + rV) & 7;
                int csw = (cVi & 8) | ((cVi & 7) ^ rsw);
                glds16(VTg + (size_t)(b * 1024 + h * 64 + row0 + rV) * 2048 + jn + csw * 8,
                       &VTs[row0 * 128]);
            }
            if (tid < 255) biasb[tid] = table[(int)lut[jn - q0 + tid + 1920] * 16 + h] * LOG2E;
            __syncthreads();
        }
    }
    // ---- epilogue: O^T lane holds (d = dt*16+quad*4+r, q = w*32+nt*16+lc) ----
#pragma unroll
    for (int nt = 0; nt < 2; ++nt) {
        float inv = 1.0f / lstate[nt];
        size_t row = tokbase + q0 + w * 32 + nt * 16 + lc;
#pragma unroll
        for (int dt = 0; dt < 4; ++dt) {
            us4 o;
#pragma unroll
            for (int r = 0; r < 4; ++r) o[r] = f2bf(acco[dt][nt][r] * inv);
            *(us4*)&Ctx[row * 1024 + h * 64 + dt * 16 + quad * 4] = o;
        }
    }
}

extern "C" void kernel_launch(void* const* d_in, const int* in_sizes, int n_in,
                              void* d_out, int out_size, void* d_ws, size_t ws_size,
                              hipStream_t stream) {
    const float* hidden = (const float*)d_in[0];
    const float* Wq = (const float*)d_in[1];
    const float* Wk = (const float*)d_in[2];
    const float* Wv = (const float*)d_in[3];
    const float* Wo = (const float*)d_in[4];
    const float* table = (const float*)d_in[5];

    char* ws = (char*)d_ws;
    ushort_t* Xb  = (ushort_t*)(ws);                    // [4096][1024] bf16
    ushort_t* Wb  = (ushort_t*)(ws + 8388608);          // Wq(*log2e),Wk,Wv,Wo each [1024][1024]
    ushort_t* Qg  = (ushort_t*)(ws + 16777216);         // [4096][1024]
    ushort_t* Kgp = (ushort_t*)(ws + 25165824);         // [4096][1024]
    ushort_t* VTg = (ushort_t*)(ws + 33554432);         // [(b*1024+f)][2048]
    ushort_t* Ctx = (ushort_t*)(ws + 41943040);         // [4096][1024]
    unsigned char* lutp = (unsigned char*)(ws + 50331648);

    float* out0 = (float*)d_out;
    float* out1 = out0 + 4194304;

    cast_all_k<<<8192, 256, 0, stream>>>(hidden, Wq, Wk, Wv, Wo, Xb, Wb);
    make_lut_k<<<16, 256, 0, stream>>>(lutp);
    write_bias_k<<<65536, 256, 0, stream>>>(lutp, table, out1);

    // Q, K projections: C[token][feat] bf16
    gemm_bt_k<0><<<dim3(8, 32, 2), 256, 0, stream>>>(Xb, Wb, (void*)Qg,
                                                     4096, 1024, 1024, 1048576, 4194304);
    // V^T: C[f][token] -> VT[(b*1024+f)][j]
    gemm_bt_k<2><<<dim3(32, 8, 1), 256, 0, stream>>>(Wb + 2097152, Xb, (void*)VTg,
                                                     1024, 4096, 1024, 0, 0);
    attn_k<<<dim3(512), 256, 0, stream>>>(Qg, Kgp, VTg, Ctx, lutp, table);
    gemm_bt_k<1><<<dim3(8, 32, 1), 256, 0, stream>>>(Ctx, Wb + 3145728, (void*)out0,
                                                     4096, 1024, 1024, 0, 0);
}

// Round 5
// 461.910 us; speedup vs baseline: 1.4603x; 1.0335x over previous
//
#include <hip/hip_runtime.h>
#include <cstdint>
#include <cmath>

typedef unsigned short ushort_t;
typedef __bf16 bf16x8 __attribute__((ext_vector_type(8)));
typedef float f32x4 __attribute__((ext_vector_type(4)));
typedef ushort_t us4 __attribute__((ext_vector_type(4)));
typedef ushort_t us8 __attribute__((ext_vector_type(8)));

#define MFMA16(a, b, c) __builtin_amdgcn_mfma_f32_16x16x32_bf16(a, b, c, 0, 0, 0)
#define LOG2E 1.4426950408889634f

__device__ __forceinline__ ushort_t f2bf(float f) {
    union { __bf16 h; ushort_t u; } cv;
    cv.h = (__bf16)f;   // RNE, lowers to HW cvt where available
    return cv.u;
}

__device__ __forceinline__ void glds16(const ushort_t* g, ushort_t* s) {
    __builtin_amdgcn_global_load_lds(
        (const __attribute__((address_space(1))) void*)(g),
        (__attribute__((address_space(3))) void*)(s), 16, 0, 0);
}

// ---------------- fused cast f32 -> bf16 (Wq pre-scaled by log2e) + bucket LUT ----------------
__global__ void cast_all_k(const float* __restrict__ x, const float* __restrict__ wq,
                           const float* __restrict__ wk, const float* __restrict__ wv,
                           const float* __restrict__ wo, ushort_t* __restrict__ xb,
                           ushort_t* __restrict__ wb, unsigned char* __restrict__ lut) {
    int id = blockIdx.x, t = threadIdx.x;
    if (id == 8192) {
        // T5 bucket LUT: delta = j - i in [-2047, 2047]
        for (int idx = t; idx < 4095; idx += 256) {
            int rel = idx - 2047;
            int bb = (rel > 0) ? 16 : 0;
            int rp = (rel < 0) ? -rel : rel;
            int add;
            if (rp < 8) {
                add = rp;
            } else {
                // match np: correctly-rounded f32 log, then f64 divide, trunc toward zero
                float lg = (float)::log((double)rp * 0.125);
                double tt = ((double)lg) / 2.772588722239781 * 8.0;
                int large = 8 + (int)tt;
                add = (large < 15) ? large : 15;
            }
            lut[idx] = (unsigned char)(bb + add);
        }
        return;
    }
    const float* src;
    ushort_t* dst;
    int idx;
    float scale = 1.0f;
    if (id < 4096) {
        src = x; dst = xb; idx = id * 256 + t;
    } else {
        int r = (id - 4096) >> 10;
        idx = ((id - 4096) & 1023) * 256 + t;
        src = (r == 0) ? wq : (r == 1) ? wk : (r == 2) ? wv : wo;
        dst = wb + (size_t)r * 1048576;
        if (r == 0) scale = LOG2E;
    }
    float4 v = ((const float4*)src)[idx];
    us4 o;
    o.x = f2bf(v.x * scale); o.y = f2bf(v.y * scale);
    o.z = f2bf(v.z * scale); o.w = f2bf(v.w * scale);
    ((us4*)dst)[idx] = o;
}

// ---------------- GEMM: C[M,N] = A[M,K] * B[N,K]^T, bf16 in, f32 acc ----------------
// 128x128 tile, BK=64, XOR-swizzled LDS (conflict-free b128 frag reads).
// MODE 0: bf16 out row-major (+z batch); MODE 1: f32 out; MODE 2: bf16 out, V^T split addressing
template <int MODE>
__global__ __launch_bounds__(256) void gemm_bt_k(const ushort_t* __restrict__ A,
                                                 const ushort_t* __restrict__ B0,
                                                 void* __restrict__ C0,
                                                 int M, int N, int K, long sB, long sC) {
    __shared__ ushort_t As[128 * 64];
    __shared__ ushort_t Bs[128 * 64];
    const int tid = threadIdx.x;
    const int l = tid & 63, w = tid >> 6;
    const int quad = l >> 4, lc = l & 15;
    const int wm = w >> 1, wn = w & 1;
    const int m0 = blockIdx.y * 128, n0 = blockIdx.x * 128;
    const ushort_t* B = B0 + (long)blockIdx.z * sB;

    f32x4 acc[4][4] = {};
    const int rA = l >> 3;
    const int cA = ((l & 7) ^ rA) * 8;   // swizzled global chunk

    for (int k0 = 0; k0 < K; k0 += 64) {
#pragma unroll
        for (int t = 0; t < 4; ++t) {
            int row = w * 32 + t * 8;
            glds16(A + (size_t)(m0 + row + rA) * K + k0 + cA, &As[row * 64]);
            glds16(B + (size_t)(n0 + row + rA) * K + k0 + cA, &Bs[row * 64]);
        }
        __syncthreads();
#pragma unroll
        for (int ko = 0; ko < 2; ++ko) {
            const int ch = (((ko * 4 + quad) ^ (lc & 7))) * 8;
            bf16x8 af[4], bfr[4];
#pragma unroll
            for (int mt = 0; mt < 4; ++mt)
                af[mt] = *(const bf16x8*)&As[(wm * 64 + mt * 16 + lc) * 64 + ch];
#pragma unroll
            for (int nt = 0; nt < 4; ++nt)
                bfr[nt] = *(const bf16x8*)&Bs[(wn * 64 + nt * 16 + lc) * 64 + ch];
#pragma unroll
            for (int mt = 0; mt < 4; ++mt)
#pragma unroll
                for (int nt = 0; nt < 4; ++nt)
                    acc[mt][nt] = MFMA16(af[mt], bfr[nt], acc[mt][nt]);
        }
        __syncthreads();
    }
#pragma unroll
    for (int mt = 0; mt < 4; ++mt) {
#pragma unroll
        for (int nt = 0; nt < 4; ++nt) {
            int col = n0 + wn * 64 + nt * 16 + lc;
#pragma unroll
            for (int r = 0; r < 4; ++r) {
                int row = m0 + wm * 64 + mt * 16 + quad * 4 + r;
                if constexpr (MODE == 1) {
                    ((float*)C0)[(size_t)row * N + col] = acc[mt][nt][r];
                } else if constexpr (MODE == 0) {
                    (((ushort_t*)C0) + (long)blockIdx.z * sC)[(size_t)row * N + col] = f2bf(acc[mt][nt][r]);
                } else {
                    // row = feature f, col = token (b*2048+j): write VT[(b*1024+f)*2048 + j]
                    ((ushort_t*)C0)[(size_t)(col >> 11) * 2097152 + (size_t)row * 2048 + (col & 2047)] =
                        f2bf(acc[mt][nt][r]);
                }
            }
        }
    }
}

// ---------------- flash attention, S^T = K*Q^T, exp2 domain, fused bias-matrix write ----------------
// 1-D grid 512: bh = id&31 (XCD-local K/V reuse), qt = id>>5. 4 waves, wave w owns q [w*32, w*32+32)
__global__ __launch_bounds__(256, 3) void attn_k(const ushort_t* __restrict__ Qg,
                                                 const ushort_t* __restrict__ Kg,
                                                 const ushort_t* __restrict__ VTg,
                                                 ushort_t* __restrict__ Ctx,
                                                 const unsigned char* __restrict__ lut,
                                                 const float* __restrict__ table,
                                                 float* __restrict__ bias_out) {
    __shared__ ushort_t Ks[128 * 64];    // [j][d] swizzled
    __shared__ ushort_t VTs[64 * 128];   // [d][j] swizzled
    __shared__ ushort_t QP[128 * 64];    // Q tile, then per-wave packed P [q][j-chunk]
    __shared__ float biasb[256];         // bias diagonal * log2e
    __shared__ float biasraw[256];       // bias diagonal raw (for bias_out patch)

    const int tid = threadIdx.x, l = tid & 63, w = tid >> 6;
    const int quad = l >> 4, lc = l & 15;
    const int id = blockIdx.x;
    const int bh = id & 31, b = bh >> 4, h = bh & 15;
    const int q0 = (id >> 5) * 128;
    const size_t tokbase = (size_t)b * 2048;

    const int rK = l >> 3;
    const int cK = ((l & 7) ^ rK) * 8;
    const int rV = l >> 4;
    const int cVi = l & 15;

    // ---- stage Q tile + K/V tile for kt=0 + bias diagonal ----
#pragma unroll
    for (int t = 0; t < 4; ++t) {
        int row0 = w * 32 + t * 8;
        glds16(Qg + (tokbase + q0 + row0 + rK) * 1024 + h * 64 + cK, &QP[row0 * 64]);
        glds16(Kg + (tokbase + row0 + rK) * 1024 + h * 64 + cK, &Ks[row0 * 64]);
    }
#pragma unroll
    for (int t = 0; t < 4; ++t) {
        int row0 = w * 16 + t * 4;
        int rsw = ((t & 1) * 4 + rV) & 7;
        int csw = (cVi & 8) | ((cVi & 7) ^ rsw);
        glds16(VTg + (size_t)(b * 1024 + h * 64 + row0 + rV) * 2048 + csw * 8, &VTs[row0 * 128]);
    }
    if (tid < 255) {
        float bvv = table[(int)lut[0 - q0 + tid + 1920] * 16 + h];
        biasraw[tid] = bvv;
        biasb[tid] = bvv * LOG2E;
    }
    __syncthreads();

    // Q fragments (B-operand): lane holds Q[w*32+nt*16+lc][ko*32+quad*8+i]
    bf16x8 qf[2][2];
#pragma unroll
    for (int nt = 0; nt < 2; ++nt)
#pragma unroll
        for (int ko = 0; ko < 2; ++ko) {
            int row = w * 32 + nt * 16 + lc;
            int ch = ((ko * 4 + quad) ^ (lc & 7)) * 8;
            qf[nt][ko] = *(const bf16x8*)&QP[row * 64 + ch];
        }
    __syncthreads();   // all qf loaded before QP is reused as packed P

    float mstate[2] = {-1e30f, -1e30f};
    float lstate[2] = {0.f, 0.f};
    f32x4 acco[4][2] = {};
    ushort_t* Pw = &QP[w * 1280];          // 32 q-rows x 40 u16 (32 j + pad)
    const int cb0 = quad * 4 - (w * 32 + lc) + 127;
    const int cxor = lc & 3;               // P chunk swizzle

    // fused bias-store geometry: this block writes i in [q0,q0+128), j-half b per kt
    const int bjf = (tid & 15) * 4 + b * 64;   // j offset within 128-tile
    const int big = tid >> 4;                  // 0..15

    for (int kt = 0; kt < 16; ++kt) {
        const int j0 = kt * 128;
        // ---- S^T = K Q^T : D[j][q], A = K rows, B = Q rows (Q pre-scaled by log2e) ----
        f32x4 accs[8][2] = {};
#pragma unroll
        for (int ko = 0; ko < 2; ++ko) {
            const int ch = ((ko * 4 + quad) ^ (lc & 7)) * 8;
#pragma unroll
            for (int mt = 0; mt < 8; ++mt) {
                bf16x8 kf = *(const bf16x8*)&Ks[(mt * 16 + lc) * 64 + ch];
                accs[mt][0] = MFMA16(kf, qf[0][ko], accs[mt][0]);
                accs[mt][1] = MFMA16(kf, qf[1][ko], accs[mt][1]);
            }
        }
        // ---- fused position_bias patch store (coalesced float4 NT stores from LDS diag) ----
        {
            float* outp = bias_out + ((size_t)h * 2048 + q0) * 2048 + j0;
#pragma unroll
            for (int rr = 0; rr < 8; ++rr) {
                int il = big + 16 * rr;
                int d0 = bjf - il + 127;
                f32x4 v;
                v[0] = biasraw[d0]; v[1] = biasraw[d0 + 1];
                v[2] = biasraw[d0 + 2]; v[3] = biasraw[d0 + 3];
                __builtin_nontemporal_store(v, (f32x4*)(outp + (size_t)il * 2048 + bjf));
            }
        }
        // ---- + bias (rolling 2-vector read: d = mt+1 for nt=0, d = mt for nt=1) ----
        f32x4 bvp;
#pragma unroll
        for (int r = 0; r < 4; ++r) bvp[r] = biasb[cb0 - 16 + r];
#pragma unroll
        for (int mt = 0; mt < 8; ++mt) {
            f32x4 bvc;
#pragma unroll
            for (int r = 0; r < 4; ++r) bvc[r] = biasb[cb0 + mt * 16 + r];
            accs[mt][0] += bvc;
            accs[mt][1] += bvp;
            bvp = bvc;
        }
        // ---- online softmax in exp2 domain: q-row = nt*16+lc over 4 quad-lanes ----
#pragma unroll
        for (int nt = 0; nt < 2; ++nt) {
            float mx = accs[0][nt][0];
#pragma unroll
            for (int mt = 0; mt < 8; ++mt)
#pragma unroll
                for (int r = 0; r < 4; ++r) mx = fmaxf(mx, accs[mt][nt][r]);
            mx = fmaxf(mx, __shfl_xor(mx, 16, 64));
            mx = fmaxf(mx, __shfl_xor(mx, 32, 64));
            float mo = mstate[nt], mn = fmaxf(mo, mx);
            float alpha = __builtin_amdgcn_exp2f(mo - mn);
            mstate[nt] = mn;
            float rs = 0.f;
#pragma unroll
            for (int mt = 0; mt < 8; ++mt)
#pragma unroll
                for (int r = 0; r < 4; ++r) {
                    float p = __builtin_amdgcn_exp2f(accs[mt][nt][r] - mn);
                    accs[mt][nt][r] = p;
                    rs += p;
                }
            rs += __shfl_xor(rs, 16, 64);
            rs += __shfl_xor(rs, 32, 64);
            lstate[nt] = lstate[nt] * alpha + rs;
#pragma unroll
            for (int dt = 0; dt < 4; ++dt) acco[dt][nt] *= alpha;
        }
        // ---- O^T += V^T P^T; P packed as [q][j-chunk] (b64 writes, b128 reads) ----
#pragma unroll
        for (int kk = 0; kk < 4; ++kk) {
#pragma unroll
            for (int half = 0; half < 2; ++half) {
                int mt = kk * 2 + half;
                int c = half * 2 + (quad >> 1);
                int coff = ((c ^ cxor) * 8 + (quad & 1) * 4);
#pragma unroll
                for (int nt = 0; nt < 2; ++nt) {
                    us4 o;
#pragma unroll
                    for (int r = 0; r < 4; ++r) o[r] = f2bf(accs[mt][nt][r]);
                    *(us4*)&Pw[(nt * 16 + lc) * 40 + coff] = o;
                }
            }
            bf16x8 pf[2];
#pragma unroll
            for (int nt = 0; nt < 2; ++nt)
                pf[nt] = *(const bf16x8*)&Pw[(nt * 16 + lc) * 40 + (quad ^ cxor) * 8];
            bf16x8 vf[4];
#pragma unroll
            for (int dt = 0; dt < 4; ++dt) {
                int ch = kk * 4 + quad;
                int chs = ((ch & 8) | ((ch & 7) ^ (lc & 7))) * 8;
                vf[dt] = *(const bf16x8*)&VTs[(dt * 16 + lc) * 128 + chs];
            }
#pragma unroll
            for (int dt = 0; dt < 4; ++dt)
#pragma unroll
                for (int nt = 0; nt < 2; ++nt)
                    acco[dt][nt] = MFMA16(vf[dt], pf[nt], acco[dt][nt]);
        }
        __syncthreads();
        if (kt < 15) {
            const int jn = j0 + 128;
#pragma unroll
            for (int t = 0; t < 4; ++t) {
                int row0 = w * 32 + t * 8;
                glds16(Kg + (tokbase + jn + row0 + rK) * 1024 + h * 64 + cK, &Ks[row0 * 64]);
            }
#pragma unroll
            for (int t = 0; t < 4; ++t) {
                int row0 = w * 16 + t * 4;
                int rsw = ((t & 1) * 4 + rV) & 7;
                int csw = (cVi & 8) | ((cVi & 7) ^ rsw);
                glds16(VTg + (size_t)(b * 1024 + h * 64 + row0 + rV) * 2048 + jn + csw * 8,
                       &VTs[row0 * 128]);
            }
            if (tid < 255) {
                float bvv = table[(int)lut[jn - q0 + tid + 1920] * 16 + h];
                biasraw[tid] = bvv;
                biasb[tid] = bvv * LOG2E;
            }
            __syncthreads();
        }
    }
    // ---- epilogue: O^T lane holds (d = dt*16+quad*4+r, q = w*32+nt*16+lc) ----
#pragma unroll
    for (int nt = 0; nt < 2; ++nt) {
        float inv = 1.0f / lstate[nt];
        size_t row = tokbase + q0 + w * 32 + nt * 16 + lc;
#pragma unroll
        for (int dt = 0; dt < 4; ++dt) {
            us4 o;
#pragma unroll
            for (int r = 0; r < 4; ++r) o[r] = f2bf(acco[dt][nt][r] * inv);
            *(us4*)&Ctx[row * 1024 + h * 64 + dt * 16 + quad * 4] = o;
        }
    }
}

extern "C" void kernel_launch(void* const* d_in, const int* in_sizes, int n_in,
                              void* d_out, int out_size, void* d_ws, size_t ws_size,
                              hipStream_t stream) {
    const float* hidden = (const float*)d_in[0];
    const float* Wq = (const float*)d_in[1];
    const float* Wk = (const float*)d_in[2];
    const float* Wv = (const float*)d_in[3];
    const float* Wo = (const float*)d_in[4];
    const float* table = (const float*)d_in[5];

    char* ws = (char*)d_ws;
    ushort_t* Xb  = (ushort_t*)(ws);                    // [4096][1024] bf16
    ushort_t* Wb  = (ushort_t*)(ws + 8388608);          // Wq(*log2e),Wk,Wv,Wo each [1024][1024]
    ushort_t* Qg  = (ushort_t*)(ws + 16777216);         // [4096][1024]
    ushort_t* Kgp = (ushort_t*)(ws + 25165824);         // [4096][1024]
    ushort_t* VTg = (ushort_t*)(ws + 33554432);         // [(b*1024+f)][2048]
    ushort_t* Ctx = (ushort_t*)(ws + 41943040);         // [4096][1024]
    unsigned char* lutp = (unsigned char*)(ws + 50331648);

    float* out0 = (float*)d_out;
    float* out1 = out0 + 4194304;

    cast_all_k<<<8193, 256, 0, stream>>>(hidden, Wq, Wk, Wv, Wo, Xb, Wb, lutp);

    // Q, K projections: C[token][feat] bf16
    gemm_bt_k<0><<<dim3(8, 32, 2), 256, 0, stream>>>(Xb, Wb, (void*)Qg,
                                                     4096, 1024, 1024, 1048576, 4194304);
    // V^T: C[f][token] -> VT[(b*1024+f)][j]
    gemm_bt_k<2><<<dim3(32, 8, 1), 256, 0, stream>>>(Wb + 2097152, Xb, (void*)VTg,
                                                     1024, 4096, 1024, 0, 0);
    attn_k<<<dim3(512), 256, 0, stream>>>(Qg, Kgp, VTg, Ctx, lutp, table, out1);
    gemm_bt_k<1><<<dim3(8, 32, 1), 256, 0, stream>>>(Ctx, Wb + 3145728, (void*)out0,
                                                     4096, 1024, 1024, 0, 0);
}

// Round 6
// 426.846 us; speedup vs baseline: 1.5802x; 1.0821x over previous
//
#include <hip/hip_runtime.h>
#include <cstdint>
#include <cmath>

typedef unsigned short ushort_t;
typedef __bf16 bf16x8 __attribute__((ext_vector_type(8)));
typedef float f32x4 __attribute__((ext_vector_type(4)));
typedef ushort_t us4 __attribute__((ext_vector_type(4)));
typedef ushort_t us8 __attribute__((ext_vector_type(8)));

#define MFMA16(a, b, c) __builtin_amdgcn_mfma_f32_16x16x32_bf16(a, b, c, 0, 0, 0)
#define LOG2E 1.4426950408889634f

__device__ __forceinline__ ushort_t f2bf(float f) {
    union { __bf16 h; ushort_t u; } cv;
    cv.h = (__bf16)f;   // RNE
    return cv.u;
}

__device__ __forceinline__ void glds16(const ushort_t* g, ushort_t* s) {
    __builtin_amdgcn_global_load_lds(
        (const __attribute__((address_space(1))) void*)(g),
        (__attribute__((address_space(3))) void*)(s), 16, 0, 0);
}

// ---------------- fused cast f32 -> bf16 (Wq pre-scaled by log2e) + bucket LUT ----------------
__global__ void cast_all_k(const float* __restrict__ x, const float* __restrict__ wq,
                           const float* __restrict__ wk, const float* __restrict__ wv,
                           const float* __restrict__ wo, ushort_t* __restrict__ xb,
                           ushort_t* __restrict__ wb, unsigned char* __restrict__ lut) {
    int id = blockIdx.x, t = threadIdx.x;
    if (id == 8192) {
        // T5 bucket LUT: delta = j - i in [-2047, 2047]
        for (int idx = t; idx < 4095; idx += 256) {
            int rel = idx - 2047;
            int bb = (rel > 0) ? 16 : 0;
            int rp = (rel < 0) ? -rel : rel;
            int add;
            if (rp < 8) {
                add = rp;
            } else {
                // match np: correctly-rounded f32 log, then f64 divide, trunc toward zero
                float lg = (float)::log((double)rp * 0.125);
                double tt = ((double)lg) / 2.772588722239781 * 8.0;
                int large = 8 + (int)tt;
                add = (large < 15) ? large : 15;
            }
            lut[idx] = (unsigned char)(bb + add);
        }
        return;
    }
    const float* src;
    ushort_t* dst;
    int idx;
    float scale = 1.0f;
    if (id < 4096) {
        src = x; dst = xb; idx = id * 256 + t;
    } else {
        int r = (id - 4096) >> 10;
        idx = ((id - 4096) & 1023) * 256 + t;
        src = (r == 0) ? wq : (r == 1) ? wk : (r == 2) ? wv : wo;
        dst = wb + (size_t)r * 1048576;
        if (r == 0) scale = LOG2E;
    }
    float4 v = ((const float4*)src)[idx];
    us4 o;
    o.x = f2bf(v.x * scale); o.y = f2bf(v.y * scale);
    o.z = f2bf(v.z * scale); o.w = f2bf(v.w * scale);
    ((us4*)dst)[idx] = o;
}

// ---------------- GEMM: C[M,N] = A[M,K] * B[N,K]^T, bf16 in, f32 acc ----------------
// 128x128 tile, BK=64, XOR-swizzled LDS (conflict-free b128 frag reads).
// MODE 0: bf16 out row-major (+z batch); MODE 1: f32 out; MODE 2: bf16 out, V^T split addressing
template <int MODE>
__global__ __launch_bounds__(256) void gemm_bt_k(const ushort_t* __restrict__ A,
                                                 const ushort_t* __restrict__ B0,
                                                 void* __restrict__ C0,
                                                 int M, int N, int K, long sB, long sC) {
    __shared__ ushort_t As[128 * 64];
    __shared__ ushort_t Bs[128 * 64];
    const int tid = threadIdx.x;
    const int l = tid & 63, w = tid >> 6;
    const int quad = l >> 4, lc = l & 15;
    const int wm = w >> 1, wn = w & 1;
    const int m0 = blockIdx.y * 128, n0 = blockIdx.x * 128;
    const ushort_t* B = B0 + (long)blockIdx.z * sB;

    f32x4 acc[4][4] = {};
    const int rA = l >> 3;
    const int cA = ((l & 7) ^ rA) * 8;   // swizzled global chunk

    for (int k0 = 0; k0 < K; k0 += 64) {
#pragma unroll
        for (int t = 0; t < 4; ++t) {
            int row = w * 32 + t * 8;
            glds16(A + (size_t)(m0 + row + rA) * K + k0 + cA, &As[row * 64]);
            glds16(B + (size_t)(n0 + row + rA) * K + k0 + cA, &Bs[row * 64]);
        }
        __syncthreads();
#pragma unroll
        for (int ko = 0; ko < 2; ++ko) {
            const int ch = (((ko * 4 + quad) ^ (lc & 7))) * 8;
            bf16x8 af[4], bfr[4];
#pragma unroll
            for (int mt = 0; mt < 4; ++mt)
                af[mt] = *(const bf16x8*)&As[(wm * 64 + mt * 16 + lc) * 64 + ch];
#pragma unroll
            for (int nt = 0; nt < 4; ++nt)
                bfr[nt] = *(const bf16x8*)&Bs[(wn * 64 + nt * 16 + lc) * 64 + ch];
#pragma unroll
            for (int mt = 0; mt < 4; ++mt)
#pragma unroll
                for (int nt = 0; nt < 4; ++nt)
                    acc[mt][nt] = MFMA16(af[mt], bfr[nt], acc[mt][nt]);
        }
        __syncthreads();
    }
#pragma unroll
    for (int mt = 0; mt < 4; ++mt) {
#pragma unroll
        for (int nt = 0; nt < 4; ++nt) {
            int col = n0 + wn * 64 + nt * 16 + lc;
#pragma unroll
            for (int r = 0; r < 4; ++r) {
                int row = m0 + wm * 64 + mt * 16 + quad * 4 + r;
                if constexpr (MODE == 1) {
                    ((float*)C0)[(size_t)row * N + col] = acc[mt][nt][r];
                } else if constexpr (MODE == 0) {
                    (((ushort_t*)C0) + (long)blockIdx.z * sC)[(size_t)row * N + col] = f2bf(acc[mt][nt][r]);
                } else {
                    // row = feature f, col = token (b*2048+j): write VT[(b*1024+f)*2048 + j]
                    ((ushort_t*)C0)[(size_t)(col >> 11) * 2097152 + (size_t)row * 2048 + (col & 2047)] =
                        f2bf(acc[mt][nt][r]);
                }
            }
        }
    }
}

// ---------------- flash attention, S^T = K*Q^T, 1 barrier/kt, K dbuf, V direct ----------------
// 1-D grid 512: bh = id&31 (XCD-local K/V reuse), qt = id>>5. 4 waves, wave w owns q [w*32, w*32+32)
__global__ __launch_bounds__(256, 2) void attn_k(const ushort_t* __restrict__ Qg,
                                                 const ushort_t* __restrict__ Kg,
                                                 const ushort_t* __restrict__ VTg,
                                                 ushort_t* __restrict__ Ctx,
                                                 const unsigned char* __restrict__ lut,
                                                 const float* __restrict__ table,
                                                 float* __restrict__ bias_out) {
    __shared__ ushort_t Kbuf[2][128 * 64];   // K tiles [j][d] swizzled, double-buffered
    __shared__ ushort_t Pws[4 * 32 * 40];    // per-wave packed P [q][j-chunk]
    __shared__ float diag[2][256];           // raw bias diagonal, double-buffered

    const int tid = threadIdx.x, l = tid & 63, w = tid >> 6;
    const int quad = l >> 4, lc = l & 15;
    const int id = blockIdx.x;
    const int bh = id & 31, b = bh >> 4, h = bh & 15;
    const int q0 = (id >> 5) * 128;
    const size_t tokbase = (size_t)b * 2048;

    const int rK = l >> 3;
    const int cK = ((l & 7) ^ rK) * 8;

    // ---- prologue: Q -> Kbuf[1], K(kt0) -> Kbuf[0], diag[0] ----
#pragma unroll
    for (int t = 0; t < 4; ++t) {
        int row0 = w * 32 + t * 8;
        glds16(Qg + (tokbase + q0 + row0 + rK) * 1024 + h * 64 + cK, &Kbuf[1][row0 * 64]);
        glds16(Kg + (tokbase + row0 + rK) * 1024 + h * 64 + cK, &Kbuf[0][row0 * 64]);
    }
    if (tid < 255) diag[0][tid] = table[(int)lut[tid + 1920 - q0] * 16 + h];
    __syncthreads();

    // Q fragments (B-operand): lane holds Q[w*32+nt*16+lc][ko*32+quad*8+i]
    bf16x8 qf[2][2];
#pragma unroll
    for (int nt = 0; nt < 2; ++nt)
#pragma unroll
        for (int ko = 0; ko < 2; ++ko) {
            int row = w * 32 + nt * 16 + lc;
            int ch = ((ko * 4 + quad) ^ (lc & 7)) * 8;
            qf[nt][ko] = *(const bf16x8*)&Kbuf[1][row * 64 + ch];
        }
    __syncthreads();   // Kbuf[1] free for kt=0's prefetch of K(kt=1)

    float mstate[2] = {-1e30f, -1e30f};
    float lstate[2] = {0.f, 0.f};
    f32x4 acco[4][2] = {};
    ushort_t* Pw = &Pws[w * 1280];         // 32 q-rows x 40 u16
    const int cb0 = quad * 4 - (w * 32 + lc) + 127;
    const int cxor = lc & 3;               // P chunk swizzle
    const ushort_t* VTbase = VTg + (size_t)(b * 1024 + h * 64) * 2048;

    const int bjf = (tid & 15) * 4 + b * 64;   // bias patch j offset within 128-tile
    const int big = tid >> 4;

    for (int kt = 0; kt < 16; ++kt) {
        const int j0 = kt * 128;
        const int cur = kt & 1, nxt = cur ^ 1;
        const ushort_t* Kc = Kbuf[cur];
        const float* dc = diag[cur];

        // ---- prefetch next K tile + next bias diagonal (drains behind this kt's compute) ----
        if (kt < 15) {
            const int jn = j0 + 128;
#pragma unroll
            for (int t = 0; t < 4; ++t) {
                int row0 = w * 32 + t * 8;
                glds16(Kg + (tokbase + jn + row0 + rK) * 1024 + h * 64 + cK, &Kbuf[nxt][row0 * 64]);
            }
            if (tid < 255) diag[nxt][tid] = table[(int)lut[jn - q0 + tid + 1920] * 16 + h];
        }

        // ---- V fragments direct from global (A-operand rows d, k-index j) ----
        bf16x8 vf[4][4];
#pragma unroll
        for (int kk = 0; kk < 4; ++kk)
#pragma unroll
            for (int dt = 0; dt < 4; ++dt)
                vf[kk][dt] = *(const bf16x8*)(VTbase + (size_t)(dt * 16 + lc) * 2048 +
                                              j0 + kk * 32 + quad * 8);

        // ---- fused position_bias patch store (issued early; drains behind compute) ----
        {
            float* outp = bias_out + ((size_t)h * 2048 + q0) * 2048 + j0;
#pragma unroll
            for (int rr = 0; rr < 8; ++rr) {
                int il = big + 16 * rr;
                int d0 = bjf - il + 127;
                f32x4 v;
                v[0] = dc[d0]; v[1] = dc[d0 + 1]; v[2] = dc[d0 + 2]; v[3] = dc[d0 + 3];
                __builtin_nontemporal_store(v, (f32x4*)(outp + (size_t)il * 2048 + bjf));
            }
        }

        // ---- S^T = K Q^T : D[j][q], A = K rows, B = Q rows (Q pre-scaled by log2e) ----
        f32x4 accs[8][2] = {};
#pragma unroll
        for (int ko = 0; ko < 2; ++ko) {
            const int ch = ((ko * 4 + quad) ^ (lc & 7)) * 8;
#pragma unroll
            for (int mt = 0; mt < 8; ++mt) {
                bf16x8 kf = *(const bf16x8*)&Kc[(mt * 16 + lc) * 64 + ch];
                accs[mt][0] = MFMA16(kf, qf[0][ko], accs[mt][0]);
                accs[mt][1] = MFMA16(kf, qf[1][ko], accs[mt][1]);
            }
        }

        // ---- + bias via fma(raw, log2e) with rolling reuse (d = mt for nt=0, mt-1 for nt=1) ----
        float dprev[4], dcur[4];
#pragma unroll
        for (int r = 0; r < 4; ++r) dprev[r] = dc[cb0 - 16 + r];
#pragma unroll
        for (int mt = 0; mt < 8; ++mt) {
#pragma unroll
            for (int r = 0; r < 4; ++r) dcur[r] = dc[cb0 + mt * 16 + r];
#pragma unroll
            for (int r = 0; r < 4; ++r) {
                accs[mt][0][r] = fmaf(dcur[r], LOG2E, accs[mt][0][r]);
                accs[mt][1][r] = fmaf(dprev[r], LOG2E, accs[mt][1][r]);
            }
#pragma unroll
            for (int r = 0; r < 4; ++r) dprev[r] = dcur[r];
        }

        // ---- online softmax in exp2 domain: q-row = nt*16+lc over 4 quad-lanes ----
#pragma unroll
        for (int nt = 0; nt < 2; ++nt) {
            float mx = accs[0][nt][0];
#pragma unroll
            for (int mt = 0; mt < 8; ++mt)
#pragma unroll
                for (int r = 0; r < 4; ++r) mx = fmaxf(mx, accs[mt][nt][r]);
            mx = fmaxf(mx, __shfl_xor(mx, 16, 64));
            mx = fmaxf(mx, __shfl_xor(mx, 32, 64));
            float mo = mstate[nt], mn = fmaxf(mo, mx);
            float alpha = __builtin_amdgcn_exp2f(mo - mn);
            mstate[nt] = mn;
            float rs = 0.f;
#pragma unroll
            for (int mt = 0; mt < 8; ++mt)
#pragma unroll
                for (int r = 0; r < 4; ++r) {
                    float p = __builtin_amdgcn_exp2f(accs[mt][nt][r] - mn);
                    accs[mt][nt][r] = p;
                    rs += p;
                }
            rs += __shfl_xor(rs, 16, 64);
            rs += __shfl_xor(rs, 32, 64);
            lstate[nt] = lstate[nt] * alpha + rs;
#pragma unroll
            for (int dt = 0; dt < 4; ++dt) acco[dt][nt] *= alpha;
        }

        // ---- O^T += V^T P^T; P packed as [q][j-chunk] (b64 writes, b128 reads) ----
#pragma unroll
        for (int kk = 0; kk < 4; ++kk) {
#pragma unroll
            for (int half = 0; half < 2; ++half) {
                int mt = kk * 2 + half;
                int c = half * 2 + (quad >> 1);
                int coff = ((c ^ cxor) * 8 + (quad & 1) * 4);
#pragma unroll
                for (int nt = 0; nt < 2; ++nt) {
                    us4 o;
#pragma unroll
                    for (int r = 0; r < 4; ++r) o[r] = f2bf(accs[mt][nt][r]);
                    *(us4*)&Pw[(nt * 16 + lc) * 40 + coff] = o;
                }
            }
            bf16x8 pf[2];
#pragma unroll
            for (int nt = 0; nt < 2; ++nt)
                pf[nt] = *(const bf16x8*)&Pw[(nt * 16 + lc) * 40 + (quad ^ cxor) * 8];
#pragma unroll
            for (int dt = 0; dt < 4; ++dt)
#pragma unroll
                for (int nt = 0; nt < 2; ++nt)
                    acco[dt][nt] = MFMA16(vf[kk][dt], pf[nt], acco[dt][nt]);
        }
        if (kt < 15) __syncthreads();   // single barrier per kt: swaps buffers + drains prefetch
    }

    // ---- epilogue: O^T lane holds (d = dt*16+quad*4+r, q = w*32+nt*16+lc) ----
#pragma unroll
    for (int nt = 0; nt < 2; ++nt) {
        float inv = 1.0f / lstate[nt];
        size_t row = tokbase + q0 + w * 32 + nt * 16 + lc;
#pragma unroll
        for (int dt = 0; dt < 4; ++dt) {
            us4 o;
#pragma unroll
            for (int r = 0; r < 4; ++r) o[r] = f2bf(acco[dt][nt][r] * inv);
            *(us4*)&Ctx[row * 1024 + h * 64 + dt * 16 + quad * 4] = o;
        }
    }
}

extern "C" void kernel_launch(void* const* d_in, const int* in_sizes, int n_in,
                              void* d_out, int out_size, void* d_ws, size_t ws_size,
                              hipStream_t stream) {
    const float* hidden = (const float*)d_in[0];
    const float* Wq = (const float*)d_in[1];
    const float* Wk = (const float*)d_in[2];
    const float* Wv = (const float*)d_in[3];
    const float* Wo = (const float*)d_in[4];
    const float* table = (const float*)d_in[5];

    char* ws = (char*)d_ws;
    ushort_t* Xb  = (ushort_t*)(ws);                    // [4096][1024] bf16
    ushort_t* Wb  = (ushort_t*)(ws + 8388608);          // Wq(*log2e),Wk,Wv,Wo each [1024][1024]
    ushort_t* Qg  = (ushort_t*)(ws + 16777216);         // [4096][1024]
    ushort_t* Kgp = (ushort_t*)(ws + 25165824);         // [4096][1024]
    ushort_t* VTg = (ushort_t*)(ws + 33554432);         // [(b*1024+f)][2048]
    ushort_t* Ctx = (ushort_t*)(ws + 41943040);         // [4096][1024]
    unsigned char* lutp = (unsigned char*)(ws + 50331648);

    float* out0 = (float*)d_out;
    float* out1 = out0 + 4194304;

    cast_all_k<<<8193, 256, 0, stream>>>(hidden, Wq, Wk, Wv, Wo, Xb, Wb, lutp);

    // Q, K projections: C[token][feat] bf16
    gemm_bt_k<0><<<dim3(8, 32, 2), 256, 0, stream>>>(Xb, Wb, (void*)Qg,
                                                     4096, 1024, 1024, 1048576, 4194304);
    // V^T: C[f][token] -> VT[(b*1024+f)][j]
    gemm_bt_k<2><<<dim3(32, 8, 1), 256, 0, stream>>>(Wb + 2097152, Xb, (void*)VTg,
                                                     1024, 4096, 1024, 0, 0);
    attn_k<<<dim3(512), 256, 0, stream>>>(Qg, Kgp, VTg, Ctx, lutp, table, out1);
    gemm_bt_k<1><<<dim3(8, 32, 1), 256, 0, stream>>>(Ctx, Wb + 3145728, (void*)out0,
                                                     4096, 1024, 1024, 0, 0);
}